// Round 7
// baseline (80.715 us; speedup 1.0000x reference)
//
#include <hip/hip_runtime.h>

// GaussianBlur 3x3 sigma=0 -> separable [0.25,0.5,0.25], BORDER_REFLECT_101.
// f32 [64,3,512,512]. One wave (64 lanes x 8 px) covers one full 512-px row;
// each thread produces 8 px in each of 2 consecutive rows. 2-row structure =
// 49152 waves (max TLP, R2's 5.0 TB/s achieved BW) + nontemporal stores
// (R4's proven FETCH 196->110 MB win). Horizontal neighbors via shuffles.

#define HH 512
#define WW 512

// native clang ext-vector: accepted by __builtin_nontemporal_store
typedef float f4 __attribute__((ext_vector_type(4)));

#define VBLUR(d, m, c, pq)                         \
    d.x = 0.25f * (m.x + pq.x) + 0.5f * c.x;       \
    d.y = 0.25f * (m.y + pq.y) + 0.5f * c.y;       \
    d.z = 0.25f * (m.z + pq.z) + 0.5f * c.z;       \
    d.w = 0.25f * (m.w + pq.w) + 0.5f * c.w;

#define HBLUR(oa, ob, ua, ub, l, r)                \
    oa.x = 0.25f * (l    + ua.y) + 0.5f * ua.x;    \
    oa.y = 0.25f * (ua.x + ua.z) + 0.5f * ua.y;    \
    oa.z = 0.25f * (ua.y + ua.w) + 0.5f * ua.z;    \
    oa.w = 0.25f * (ua.z + ub.x) + 0.5f * ua.w;    \
    ob.x = 0.25f * (ua.w + ub.y) + 0.5f * ub.x;    \
    ob.y = 0.25f * (ub.x + ub.z) + 0.5f * ub.y;    \
    ob.z = 0.25f * (ub.y + ub.w) + 0.5f * ub.z;    \
    ob.w = 0.25f * (ub.z + r   ) + 0.5f * ub.w;

__global__ __launch_bounds__(256) void gauss3_kernel(const float* __restrict__ in,
                                                     float* __restrict__ out) {
    int wid  = (blockIdx.x * 256 + threadIdx.x) >> 6;  // global wave id
    int lane = threadIdx.x & 63;

    int rowpair = wid & 255;   // 256 row-pairs per (b,c) plane
    int plane   = wid >> 8;

    int h0 = rowpair << 1;
    int h1 = h0 + 1;
    int hm = (h0 == 0)      ? 1      : h0 - 1;   // reflect-101
    int hp = (h1 == HH - 1) ? HH - 2 : h1 + 1;   // reflect-101

    const float* p = in  + (size_t)plane * (HH * WW);
    float*       q = out + (size_t)plane * (HH * WW);
    int w0 = lane << 3;  // 8 px per lane

    const f4* Lm = (const f4*)(p + (size_t)hm * WW + w0);
    const f4* L0 = (const f4*)(p + (size_t)h0 * WW + w0);
    const f4* L1 = (const f4*)(p + (size_t)h1 * WW + w0);
    const f4* Lp = (const f4*)(p + (size_t)hp * WW + w0);

    // 8 wide loads up front (MLP)
    f4 am0 = Lm[0], am1 = Lm[1];
    f4 a00 = L0[0], a01 = L0[1];
    f4 a10 = L1[0], a11 = L1[1];
    f4 ap0 = Lp[0], ap1 = Lp[1];

    // vertical blur: row h0 uses (hm, h0, h1); row h1 uses (h0, h1, hp)
    f4 u0a, u0b, u1a, u1b;
    VBLUR(u0a, am0, a00, a10)
    VBLUR(u0b, am1, a01, a11)
    VBLUR(u1a, a00, a10, ap0)
    VBLUR(u1b, a01, a11, ap1)

    // horizontal edge neighbors from adjacent lanes
    float l0 = __shfl_up(u0b.w, 1);
    float l1 = __shfl_up(u1b.w, 1);
    float r0 = __shfl_down(u0a.x, 1);
    float r1 = __shfl_down(u1a.x, 1);
    if (lane == 0)  { l0 = u0a.y; l1 = u1a.y; }   // reflect: in[-1] == in[1]
    if (lane == 63) { r0 = u0b.z; r1 = u1b.z; }   // reflect: in[512] == in[510]

    f4 o0a, o0b, o1a, o1b;
    HBLUR(o0a, o0b, u0a, u0b, l0, r0)
    HBLUR(o1a, o1b, u1a, u1b, l1, r1)

    f4* S0 = (f4*)(q + (size_t)h0 * WW + w0);
    f4* S1 = (f4*)(q + (size_t)h1 * WW + w0);
    __builtin_nontemporal_store(o0a, S0);
    __builtin_nontemporal_store(o0b, S0 + 1);
    __builtin_nontemporal_store(o1a, S1);
    __builtin_nontemporal_store(o1b, S1 + 1);
}

extern "C" void kernel_launch(void* const* d_in, const int* in_sizes, int n_in,
                              void* d_out, int out_size, void* d_ws, size_t ws_size,
                              hipStream_t stream) {
    const float* x   = (const float*)d_in[0];
    float*       out = (float*)d_out;

    int n      = in_sizes[0];          // 64*3*512*512
    int planes = n / (HH * WW);        // 192
    int waves  = planes * (HH / 2);    // one wave per row-pair: 49152
    int blocks = waves / 4;            // 4 waves per 256-thread block: 12288

    gauss3_kernel<<<blocks, 256, 0, stream>>>(x, out);
}

// Round 8
// 77.971 us; speedup vs baseline: 1.0352x; 1.0352x over previous
//
#include <hip/hip_runtime.h>

// GaussianBlur 3x3 sigma=0 -> separable [0.25,0.5,0.25], BORDER_REFLECT_101.
// f32 [64,3,512,512]. One wave covers one full 512-px row (8 px/lane);
// persistent waves each handle 3 row-quads (4 output rows each) with
// software-pipelined double buffering: next quad's 12 b128 loads are issued
// BEFORE current quad's compute/stores, pinned with sched_barrier(0) so the
// scheduler can't sink them (R5/R6 showed it otherwise collapses the window
// to VGPR=32). NT stores keep input L3-resident. Shuffle edge exchange.

#define HH 512
#define WW 512

typedef float f4 __attribute__((ext_vector_type(4)));

struct Quad {
    f4 ma, mb, a0a, a0b, a1a, a1b, a2a, a2b, a3a, a3b, pa, pb;
};

#define VBLUR(d, m, c, pq)                         \
    d.x = 0.25f * (m.x + pq.x) + 0.5f * c.x;       \
    d.y = 0.25f * (m.y + pq.y) + 0.5f * c.y;       \
    d.z = 0.25f * (m.z + pq.z) + 0.5f * c.z;       \
    d.w = 0.25f * (m.w + pq.w) + 0.5f * c.w;

#define HBLUR(oa, ob, ua, ub, l, r)                \
    oa.x = 0.25f * (l    + ua.y) + 0.5f * ua.x;    \
    oa.y = 0.25f * (ua.x + ua.z) + 0.5f * ua.y;    \
    oa.z = 0.25f * (ua.y + ua.w) + 0.5f * ua.z;    \
    oa.w = 0.25f * (ua.z + ub.x) + 0.5f * ua.w;    \
    ob.x = 0.25f * (ua.w + ub.y) + 0.5f * ub.x;    \
    ob.y = 0.25f * (ub.x + ub.z) + 0.5f * ub.y;    \
    ob.z = 0.25f * (ub.y + ub.w) + 0.5f * ub.z;    \
    ob.w = 0.25f * (ub.z + r   ) + 0.5f * ub.w;

// vertical blur of (ma,mb|ca,cb|pa,pb), shuffle edges, horizontal blur,
// NT store one output row at S
#define ROW(ma_, mb_, ca_, cb_, pa_, pb_, S)                         \
    {                                                                \
        f4 ua, ub;                                                   \
        VBLUR(ua, ma_, ca_, pa_)                                     \
        VBLUR(ub, mb_, cb_, pb_)                                     \
        float l = __shfl_up(ub.w, 1);                                \
        float r = __shfl_down(ua.x, 1);                              \
        if (lane == 0)  l = ua.y;                                    \
        if (lane == 63) r = ub.z;                                    \
        f4 oa, ob;                                                   \
        HBLUR(oa, ob, ua, ub, l, r)                                  \
        __builtin_nontemporal_store(oa, (S));                        \
        __builtin_nontemporal_store(ob, (S) + 1);                    \
    }

__device__ __forceinline__ void load_quad(const float* __restrict__ in, int q,
                                          int w0, Quad& Q) {
    int plane = q >> 7;                 // 128 quads per (b,c) plane
    int h0    = (q & 127) << 2;
    int hm = (h0 == 0)      ? 1       : h0 - 1;   // reflect-101
    int hp = (h0 + 4 == HH) ? HH - 2  : h0 + 4;   // reflect-101
    const float* base = in + (size_t)plane * (HH * WW) + w0;
    const f4* Lm = (const f4*)(base + (size_t)hm       * WW);
    const f4* L0 = (const f4*)(base + (size_t)h0       * WW);
    const f4* L1 = (const f4*)(base + (size_t)(h0 + 1) * WW);
    const f4* L2 = (const f4*)(base + (size_t)(h0 + 2) * WW);
    const f4* L3 = (const f4*)(base + (size_t)(h0 + 3) * WW);
    const f4* Lp = (const f4*)(base + (size_t)hp       * WW);
    Q.ma  = Lm[0]; Q.mb  = Lm[1];
    Q.a0a = L0[0]; Q.a0b = L0[1];
    Q.a1a = L1[0]; Q.a1b = L1[1];
    Q.a2a = L2[0]; Q.a2b = L2[1];
    Q.a3a = L3[0]; Q.a3b = L3[1];
    Q.pa  = Lp[0]; Q.pb  = Lp[1];
}

__device__ __forceinline__ void comp_quad(float* __restrict__ out, int q,
                                          int lane, int w0, const Quad& Q) {
    int plane = q >> 7;
    int h0    = (q & 127) << 2;
    float* base = out + (size_t)plane * (HH * WW) + w0;
    ROW(Q.ma,  Q.mb,  Q.a0a, Q.a0b, Q.a1a, Q.a1b, (f4*)(base + (size_t)h0       * WW))
    ROW(Q.a0a, Q.a0b, Q.a1a, Q.a1b, Q.a2a, Q.a2b, (f4*)(base + (size_t)(h0 + 1) * WW))
    ROW(Q.a1a, Q.a1b, Q.a2a, Q.a2b, Q.a3a, Q.a3b, (f4*)(base + (size_t)(h0 + 2) * WW))
    ROW(Q.a2a, Q.a2b, Q.a3a, Q.a3b, Q.pa,  Q.pb,  (f4*)(base + (size_t)(h0 + 3) * WW))
}

__global__ __launch_bounds__(256, 3) void gauss3_kernel(const float* __restrict__ in,
                                                        float* __restrict__ out) {
    int wid  = (blockIdx.x * 256 + threadIdx.x) >> 6;  // 0..8191
    int lane = threadIdx.x & 63;
    int w0   = lane << 3;  // 8 px per lane

    // 24576 quads total; this wave handles q0, q0+8192, q0+16384
    int q0 = wid, q1 = wid + 8192, q2 = wid + 16384;

    Quad A, B, C;
    load_quad(in, q0, w0, A);
    load_quad(in, q1, w0, B);            // 24 loads in flight
    __builtin_amdgcn_sched_barrier(0);   // pin: B loads may not sink below
    comp_quad(out, q0, lane, w0, A);
    load_quad(in, q2, w0, C);            // issue ahead of B's compute
    __builtin_amdgcn_sched_barrier(0);   // pin: C loads may not sink below
    comp_quad(out, q1, lane, w0, B);
    comp_quad(out, q2, lane, w0, C);
}

extern "C" void kernel_launch(void* const* d_in, const int* in_sizes, int n_in,
                              void* d_out, int out_size, void* d_ws, size_t ws_size,
                              hipStream_t stream) {
    const float* x   = (const float*)d_in[0];
    float*       out = (float*)d_out;

    // 192 planes x 128 quads = 24576 quads; 8192 persistent waves x 3 quads
    int blocks = 2048;  // x 256 threads = 8192 waves
    gauss3_kernel<<<blocks, 256, 0, stream>>>(x, out);
}